// Round 6
// baseline (372.724 us; speedup 1.0000x reference)
//
#include <hip/hip_runtime.h>
#include <stdint.h>

#define BATCH 4
#define SEQ   2048
#define NH    16
#define HD    128
#define HID   2048
#define N3    6144

typedef _Float16 f16;
typedef _Float16 f16x8 __attribute__((ext_vector_type(8)));
typedef _Float16 f16x4 __attribute__((ext_vector_type(4)));
typedef float    f32x4 __attribute__((ext_vector_type(4)));

// log2(e)/sqrt(HD): softmax computed in exp2 domain, scale folded into Q
#define QSCALE 0.1275313895f

// lengths may arrive as int32 or int64. int64 storage of lengths[0]=2048 puts
// 0 at word index 1; int32 puts 1024.
__device__ __forceinline__ int get_len(const int* L, int b) {
  return (L[1] == 0) ? L[2 * b] : L[b];
}

// NOTE: lds_uniform MUST be wave-uniform; HW writes lane i at base + i*16.
__device__ __forceinline__ void async_copy16(void* lds_uniform, const void* gptr) {
  __builtin_amdgcn_global_load_lds(
      (const __attribute__((address_space(1))) void*)(uintptr_t)gptr,
      (__attribute__((address_space(3))) void*)(uint32_t)(uintptr_t)lds_uniform,
      16, 0, 0);
}

// ---------------- kernel 0: fused x->fp16 and W->Wt fp16 ------------------
// R2's 64B-window chunk swizzle (measured 0 LDS conflicts):
//   p = (g & ~3) | ((g ^ ((row>>1)&3)) & 3)   [g = 8-f16 chunk index]
__global__ __launch_bounds__(256) void cvt_fused(const float* __restrict__ x,
                                                 f16* __restrict__ xh,
                                                 const float* __restrict__ W,
                                                 f16* __restrict__ Wt) {
  __shared__ float tile[64][65];
  if (blockIdx.x < 8192) {
    // ---- x [8192][2048] fp32 -> xh fp16, swizzled ----
    int idx = blockIdx.x * 256 + threadIdx.x;  // one 8-elem chunk per thread
    int m = idx >> 8;                          // 256 chunks per 2048-wide row
    int g = idx & 255;
    int p = (g & ~3) | ((g ^ ((m >> 1) & 3)) & 3);
    const float* src = x + (size_t)m * HID + g * 8;
    f16x8 o;
#pragma unroll
    for (int j = 0; j < 8; ++j) o[j] = (f16)src[j];
    *(f16x8*)&xh[(size_t)m * HID + p * 8] = o;
  } else {
    // ---- W [K=2048][N=6144] fp32 -> Wt [N][K] fp16, swizzled ----
    int bid = blockIdx.x - 8192;               // 0..3071
    const int n0 = (bid % 96) * 64;
    const int k0 = (bid / 96) * 64;
    const int tid = threadIdx.x;
#pragma unroll
    for (int i = 0; i < 4; ++i) {
      int id = tid + i * 256;
      int kr = id >> 4, nc = id & 15;
      f32x4 v = *(const f32x4*)&W[(size_t)(k0 + kr) * N3 + n0 + nc * 4];
#pragma unroll
      for (int j = 0; j < 4; ++j) tile[kr][nc * 4 + j] = v[j];
    }
    __syncthreads();
#pragma unroll
    for (int i = 0; i < 2; ++i) {
      int id = tid + i * 256;
      int nl = id >> 3;       // 0..63 local n
      int kc = id & 7;        // 8 k-chunks of 8
      f16x8 o;
#pragma unroll
      for (int j = 0; j < 8; ++j) o[j] = (f16)tile[kc * 8 + j][nl];
      int n = n0 + nl;
      int gk = (k0 >> 3) + kc;       // k0 is 64-aligned -> gk&3 == kc&3
      int p = (gk & ~3) | ((gk ^ ((n >> 1) & 3)) & 3);
      *(f16x8*)&Wt[(size_t)n * HID + p * 8] = o;
    }
  }
}

// ---------------- kernel 1: QKV GEMM (round-0 128x128, measured 117us) ----
__global__ __launch_bounds__(256, 3)
void qkv_gemm(const f16* __restrict__ xh, const f16* __restrict__ Wt,
              const float* __restrict__ bias, const int* __restrict__ lens,
              f16* __restrict__ Qh, f16* __restrict__ Kh, f16* __restrict__ Vt) {
  __shared__ f16 As[2 * 128 * 32];   // 16 KB  [half][row][32]
  __shared__ f16 Bs[2 * 128 * 32];   // 16 KB

  const int tid = threadIdx.x;
  const int wave = tid >> 6, lane = tid & 63;
  const int lr = lane & 15, quad = lane >> 4;
  const int nblk = blockIdx.x;   // 0..47  (t,h)
  const int mblk = blockIdx.y;   // 0..63
  const int m0 = mblk * 128;
  const int b = m0 >> 11;
  const int s0 = m0 & (SEQ - 1);
  const int len = get_len(lens, b);
  if (s0 >= len) return;         // fully-dead M-tile
  const int n0 = nblk * 128;
  const int wr = (wave >> 1) * 64;
  const int wc = (wave & 1) * 64;

  f32x4 acc[4][4] = {};
  const char* xbase = (const char*)xh + (size_t)m0 * (HID * 2);
  const char* wbase = (const char*)Wt + (size_t)n0 * (HID * 2);

  for (int k0 = 0; k0 < HID; k0 += 64) {
    __syncthreads();
#pragma unroll
    for (int i = 0; i < 4; ++i) {
      int slot = wave * 4 + i;          // 0..15
      int hh = slot >> 3;               // k-half
      int sub = slot & 7;
      int row = sub * 16 + (lane >> 2);
      size_t gcol = (size_t)k0 * 2 + hh * 64 + (lane & 3) * 16;
      async_copy16(&As[slot * 512], xbase + (size_t)row * (HID * 2) + gcol);
      async_copy16(&Bs[slot * 512], wbase + (size_t)row * (HID * 2) + gcol);
    }
    __syncthreads();

#pragma unroll
    for (int hh = 0; hh < 2; ++hh) {
      f16x8 a[4], bf[4];
#pragma unroll
      for (int mt = 0; mt < 4; ++mt) {
        int row = wr + mt * 16 + lr;
        int c = quad ^ ((row >> 1) & 3);
        a[mt] = *(const f16x8*)&As[hh * 4096 + row * 32 + c * 8];
      }
#pragma unroll
      for (int nt = 0; nt < 4; ++nt) {
        int row = wc + nt * 16 + lr;
        int c = quad ^ ((row >> 1) & 3);
        bf[nt] = *(const f16x8*)&Bs[hh * 4096 + row * 32 + c * 8];
      }
#pragma unroll
      for (int mt = 0; mt < 4; ++mt)
#pragma unroll
        for (int nt = 0; nt < 4; ++nt)
          acc[mt][nt] = __builtin_amdgcn_mfma_f32_16x16x32_f16(a[mt], bf[nt],
                                                               acc[mt][nt], 0, 0, 0);
    }
  }

  const int t = nblk >> 4;        // 0=q 1=k 2=v
  const int h = nblk & 15;
  const size_t bhoff = (size_t)(b * NH + h);

  if (t == 0) {
    f16* qp = Qh + bhoff * (SEQ * HD);
#pragma unroll
    for (int nt = 0; nt < 4; ++nt) {
      int d = wc + nt * 16 + lr;
      float bv = bias[n0 + d];
#pragma unroll
      for (int mt = 0; mt < 4; ++mt) {
        int sb = s0 + wr + mt * 16 + quad * 4;
#pragma unroll
        for (int r = 0; r < 4; ++r)
          qp[(size_t)(sb + r) * HD + d] = (f16)((acc[mt][nt][r] + bv) * QSCALE);
      }
    }
  } else if (t == 1) {
    f16* kp = Kh + bhoff * (SEQ * HD);
#pragma unroll
    for (int nt = 0; nt < 4; ++nt) {
      int d = wc + nt * 16 + lr;
      float bv = bias[n0 + d];
#pragma unroll
      for (int mt = 0; mt < 4; ++mt) {
        int sb = s0 + wr + mt * 16 + quad * 4;
#pragma unroll
        for (int r = 0; r < 4; ++r) {
          int s = sb + r;
          int c = (d >> 3) ^ (s & 15);            // chunk swizzle by s
          kp[(size_t)s * HD + c * 8 + (d & 7)] = (f16)(acc[mt][nt][r] + bv);
        }
      }
    }
  } else {
    f16* vp = Vt + bhoff * (HD * SEQ);            // transposed plane [d][s]
#pragma unroll
    for (int nt = 0; nt < 4; ++nt) {
      int d = wc + nt * 16 + lr;
      float bv = bias[n0 + d];
#pragma unroll
      for (int mt = 0; mt < 4; ++mt) {
        int sb = s0 + wr + mt * 16 + quad * 4;    // multiple of 4
        f16x4 pk;
#pragma unroll
        for (int r = 0; r < 4; ++r) pk[r] = (f16)(acc[mt][nt][r] + bv);
        int p = (sb >> 3) ^ (d & 7);              // s-chunk swizzle by d
        *(f16x4*)&vp[(size_t)d * SEQ + p * 8 + (sb & 7)] = pk;
      }
    }
  }
}

// ---------------- kernel 2: flash attention, in-register P -----------------
// 256 threads (4 waves x 32 q-rows). Swapped QK^T: sacc = mfma(K,Q) gives
// S^T[key=nt*16+quad*4+r][q=lr] -- exactly the B-frag layout of
// mfma_f32_16x16x16f16 (k=quad*4+reg, col=lr). So P never touches LDS:
// PV = mfma(V_frag, cvt_f16(exp2(sacc))). Each wave reads Ks/Vs once per
// 64 output MFMAs (2 row-groups) -> LDS ~1664 cyc vs MFMA ~1560 per
// block-tile (was 4000 vs 1242). K/V staged via global_load_lds with
// WAVE-UNIFORM LDS base (HW scatters lane*16; round-4 container kill was
// traced to a divergent LDS pointer here). Single-buffered, 3 barriers/tile:
//   [barC: Ks ready] QK^T; softmax+pack; W0; barA (Vs ready + Ks free);
//   stageK(kt+1); PV; barB (Vs free); stageV(kt+1); W4 (Ks' landed); barC.
// lrow is per-lane (q=lr), reduced with shfl_xor(16,32) at the end.
__global__ __launch_bounds__(256, 3)
void attn(const f16* __restrict__ Qh, const f16* __restrict__ Kh,
          const f16* __restrict__ Vt, const int* __restrict__ lens,
          float* __restrict__ out) {
  __shared__ f16 Ks[64 * 128];   // [key][d]  swizzled, 16KB
  __shared__ f16 Vs[128 * 64];   // [d][key]  swizzled, 16KB

  const int tid = threadIdx.x, wave = tid >> 6, lane = tid & 63;
  const int lr = lane & 15, quad = lane >> 4;
  // decode XCD-swizzled id: id = (bh&7) + 8*(qt + 16*(bh>>3))
  const int id = blockIdx.x;
  const int bhlo = id & 7;
  const int r3 = id >> 3;
  const int qt = r3 & 15;
  const int bh = ((r3 >> 4) << 3) | bhlo;
  const int b = bh >> 4, h = bh & 15;
  const int len = get_len(lens, b);
  const int q0 = qt * 128;
  const size_t bho = (size_t)(b * NH + h);
  float* obase = out + bho * (size_t)(SEQ * HD);

  if (q0 >= len) {               // fully-invalid q-tile: write exact zeros
    f32x4 z = {0.f, 0.f, 0.f, 0.f};
#pragma unroll
    for (int i = 0; i < 16; ++i) {
      int idx = tid + i * 256;
      *(f32x4*)&obase[(size_t)q0 * HD + (size_t)idx * 4] = z;
    }
    return;
  }

  // Q fragments resident in registers: wave owns 32 q-rows (2 groups of 16)
  f16x8 qa[2][4];
  {
    const f16* qp = Qh + bho * (size_t)(SEQ * HD);
#pragma unroll
    for (int rg = 0; rg < 2; ++rg) {
      int row = q0 + wave * 32 + rg * 16 + lr;
#pragma unroll
      for (int ks = 0; ks < 4; ++ks)
        qa[rg][ks] = *(const f16x8*)&qp[(size_t)row * HD + ks * 32 + quad * 8];
    }
  }

  float lrow[2] = {0.f, 0.f};
  f32x4 oacc[2][8] = {};

  const char* kpl = (const char*)(Kh + bho * (size_t)(SEQ * HD));
  const char* vpl = (const char*)(Vt + bho * (size_t)(HD * SEQ));

  const int nkt = (len + 63) >> 6;

  // DMA staging: 16 slots of 1KB each for K and V; wave stages 4 of each.
  // LDS dest = slot base (uniform); lane i's 16B chunk comes from its global
  // src and lands at base + i*16 (HW scatter) = &Ks[slot*512 + i*8].
  // K slot: keys slot*4..+3, all 128 d (row-linear, already chunk-swizzled).
  // V slot: d-rows slot*8..+7, 64 keys (row-linear, already chunk-swizzled).
  auto stageK = [&](int kt) {
    size_t koff = (size_t)kt * 64;
#pragma unroll
    for (int j = 0; j < 4; ++j) {
      int slot = wave * 4 + j;
      const char* src = kpl +
          ((koff + slot * 4 + (lane >> 4)) * HD + (size_t)(lane & 15) * 8) * 2;
      async_copy16(&Ks[slot * 512], src);
    }
  };
  auto stageV = [&](int kt) {
    size_t koff = (size_t)kt * 64;
#pragma unroll
    for (int j = 0; j < 4; ++j) {
      int slot = wave * 4 + j;
      const char* src = vpl +
          ((size_t)(slot * 8 + (lane >> 3)) * SEQ + koff + (size_t)(lane & 7) * 8) * 2;
      async_copy16(&Vs[slot * 512], src);
    }
  };

  stageK(0);
  stageV(0);
  asm volatile("s_waitcnt vmcnt(0)" ::: "memory");
  __builtin_amdgcn_s_barrier();

  for (int kt = 0; kt < nkt; ++kt) {
    // S^T = K @ Q^T  (exp2 domain; scale pre-folded into Q)
    f32x4 sacc[2][4] = {};
#pragma unroll
    for (int ks = 0; ks < 4; ++ks) {
      f16x8 kb[4];
#pragma unroll
      for (int nt = 0; nt < 4; ++nt) {
        int key = nt * 16 + lr;
        int c = (ks * 4 + quad) ^ (key & 15);
        kb[nt] = *(const f16x8*)&Ks[key * 128 + c * 8];
      }
#pragma unroll
      for (int nt = 0; nt < 4; ++nt) {
        sacc[0][nt] = __builtin_amdgcn_mfma_f32_16x16x32_f16(kb[nt], qa[0][ks],
                                                             sacc[0][nt], 0, 0, 0);
        sacc[1][nt] = __builtin_amdgcn_mfma_f32_16x16x32_f16(kb[nt], qa[1][ks],
                                                             sacc[1][nt], 0, 0, 0);
      }
    }

    // jagged mask (last tile only): key = kbase + nt*16 + quad*4 + r
    const int kbase = kt * 64;
    if (kbase + 64 > len) {
#pragma unroll
      for (int nt = 0; nt < 4; ++nt)
#pragma unroll
        for (int r = 0; r < 4; ++r)
          if (kbase + nt * 16 + quad * 4 + r >= len) {
            sacc[0][nt][r] = -3.0e38f;
            sacc[1][nt][r] = -3.0e38f;
          }
    }

    // fixed-shift softmax in-register: p = exp2(s); pack to f16 B-frags
    f16x4 pb[2][4];
#pragma unroll
    for (int rg = 0; rg < 2; ++rg)
#pragma unroll
      for (int nt = 0; nt < 4; ++nt) {
        float e0 = __builtin_amdgcn_exp2f(sacc[rg][nt][0]);
        float e1 = __builtin_amdgcn_exp2f(sacc[rg][nt][1]);
        float e2 = __builtin_amdgcn_exp2f(sacc[rg][nt][2]);
        float e3 = __builtin_amdgcn_exp2f(sacc[rg][nt][3]);
        lrow[rg] += (e0 + e1) + (e2 + e3);
        f16x4 pk = {(f16)e0, (f16)e1, (f16)e2, (f16)e3};
        pb[rg][nt] = pk;
      }

    const int ktn = (kt + 1 < nkt) ? kt + 1 : nkt - 1;  // clamp: re-stage ok
    asm volatile("s_waitcnt vmcnt(0)" ::: "memory");    // my Vs copies landed
    __builtin_amdgcn_s_barrier();                        // barA: Vs ready, Ks free
    stageK(ktn);

    // O^T += V^T @ P^T  (A = V-frag k=quad*4..+3, B = pb)
#pragma unroll
    for (int dt = 0; dt < 8; ++dt) {
      int d = dt * 16 + lr;
      f16x4 va[4];
#pragma unroll
      for (int nt = 0; nt < 4; ++nt) {
        int cc = (nt * 2 + (quad >> 1)) ^ (d & 7);
        va[nt] = *(const f16x4*)&Vs[d * 64 + cc * 8 + (quad & 1) * 4];
      }
#pragma unroll
      for (int nt = 0; nt < 4; ++nt) {
        oacc[0][dt] = __builtin_amdgcn_mfma_f32_16x16x16f16(va[nt], pb[0][nt],
                                                            oacc[0][dt], 0, 0, 0);
        oacc[1][dt] = __builtin_amdgcn_mfma_f32_16x16x16f16(va[nt], pb[1][nt],
                                                            oacc[1][dt], 0, 0, 0);
      }
    }

    __builtin_amdgcn_s_barrier();                        // barB: Vs free
    stageV(ktn);
    asm volatile("s_waitcnt vmcnt(4)" ::: "memory");     // my Ks' copies landed
    __builtin_amdgcn_s_barrier();                        // barC: Ks' ready
  }
  asm volatile("s_waitcnt vmcnt(0)" ::: "memory");       // drain before endpgm

  // finalize: lanes lr, lr+16, lr+32, lr+48 share q-row -> xor 16/32
  float linv[2];
#pragma unroll
  for (int rg = 0; rg < 2; ++rg) {
    float l = lrow[rg];
    l += __shfl_xor(l, 16);
    l += __shfl_xor(l, 32);
    linv[rg] = 1.0f / l;
  }
#pragma unroll
  for (int rg = 0; rg < 2; ++rg) {
    int s = q0 + wave * 32 + rg * 16 + lr;
    bool valid = s < len;
#pragma unroll
    for (int dt = 0; dt < 8; ++dt) {
      f32x4 o;
#pragma unroll
      for (int r = 0; r < 4; ++r)
        o[r] = valid ? oacc[rg][dt][r] * linv[rg] : 0.0f;
      *(f32x4*)&obase[(size_t)s * HD + dt * 16 + quad * 4] = o;
    }
  }
}

extern "C" void kernel_launch(void* const* d_in, const int* in_sizes, int n_in,
                              void* d_out, int out_size, void* d_ws, size_t ws_size,
                              hipStream_t stream) {
  const float* x = (const float*)d_in[0];
  const float* W = (const float*)d_in[1];
  const float* bias = (const float*)d_in[2];
  const int* lens = (const int*)d_in[3];
  float* out = (float*)d_out;

  char* ws = (char*)d_ws;
  size_t off = 0;
  f16* xh = (f16*)(ws + off); off += (size_t)BATCH * SEQ * HID * 2;   // 32MB
  f16* Wt = (f16*)(ws + off); off += (size_t)N3 * HID * 2;            // 24MB
  f16* Qh = (f16*)(ws + off); off += (size_t)BATCH * NH * SEQ * HD * 2;
  f16* Kh = (f16*)(ws + off); off += (size_t)BATCH * NH * SEQ * HD * 2;
  f16* Vt = (f16*)(ws + off); off += (size_t)BATCH * NH * SEQ * HD * 2;
  // total ws use: ~152 MB

  cvt_fused<<<8192 + 3072, 256, 0, stream>>>(x, xh, W, Wt);
  qkv_gemm<<<dim3(48, 64), 256, 0, stream>>>(xh, Wt, bias, lens, Qh, Kh, Vt);
  attn<<<1024, 256, 0, stream>>>(Qh, Kh, Vt, lens, out);
}

// Round 8
// 333.746 us; speedup vs baseline: 1.1168x; 1.1168x over previous
//
#include <hip/hip_runtime.h>
#include <stdint.h>

#define BATCH 4
#define SEQ   2048
#define NH    16
#define HD    128
#define HID   2048
#define N3    6144

typedef _Float16 f16;
typedef _Float16 f16x8 __attribute__((ext_vector_type(8)));
typedef _Float16 f16x4 __attribute__((ext_vector_type(4)));
typedef float    f32x4 __attribute__((ext_vector_type(4)));

// log2(e)/sqrt(HD): softmax computed in exp2 domain, scale folded into Q
#define QSCALE 0.1275313895f

// lengths may arrive as int32 or int64. int64 storage of lengths[0]=2048 puts
// 0 at word index 1; int32 puts 1024.
__device__ __forceinline__ int get_len(const int* L, int b) {
  return (L[1] == 0) ? L[2 * b] : L[b];
}

// NOTE: lds_uniform MUST be wave-uniform; HW writes lane i at base + i*16.
__device__ __forceinline__ void async_copy16(void* lds_uniform, const void* gptr) {
  __builtin_amdgcn_global_load_lds(
      (const __attribute__((address_space(1))) void*)(uintptr_t)gptr,
      (__attribute__((address_space(3))) void*)(uint32_t)(uintptr_t)lds_uniform,
      16, 0, 0);
}

// ---------------- kernel 0: fused x->fp16 and W->Wt fp16 ------------------
// R2's 64B-window chunk swizzle (measured 0 LDS conflicts):
//   p = (g & ~3) | ((g ^ ((row>>1)&3)) & 3)   [g = 8-f16 chunk index]
__global__ __launch_bounds__(256) void cvt_fused(const float* __restrict__ x,
                                                 f16* __restrict__ xh,
                                                 const float* __restrict__ W,
                                                 f16* __restrict__ Wt) {
  __shared__ float tile[64][65];
  if (blockIdx.x < 8192) {
    // ---- x [8192][2048] fp32 -> xh fp16, swizzled ----
    int idx = blockIdx.x * 256 + threadIdx.x;  // one 8-elem chunk per thread
    int m = idx >> 8;                          // 256 chunks per 2048-wide row
    int g = idx & 255;
    int p = (g & ~3) | ((g ^ ((m >> 1) & 3)) & 3);
    const float* src = x + (size_t)m * HID + g * 8;
    f16x8 o;
#pragma unroll
    for (int j = 0; j < 8; ++j) o[j] = (f16)src[j];
    *(f16x8*)&xh[(size_t)m * HID + p * 8] = o;
  } else {
    // ---- W [K=2048][N=6144] fp32 -> Wt [N][K] fp16, swizzled ----
    int bid = blockIdx.x - 8192;               // 0..3071
    const int n0 = (bid % 96) * 64;
    const int k0 = (bid / 96) * 64;
    const int tid = threadIdx.x;
#pragma unroll
    for (int i = 0; i < 4; ++i) {
      int id = tid + i * 256;
      int kr = id >> 4, nc = id & 15;
      f32x4 v = *(const f32x4*)&W[(size_t)(k0 + kr) * N3 + n0 + nc * 4];
#pragma unroll
      for (int j = 0; j < 4; ++j) tile[kr][nc * 4 + j] = v[j];
    }
    __syncthreads();
#pragma unroll
    for (int i = 0; i < 2; ++i) {
      int id = tid + i * 256;
      int nl = id >> 3;       // 0..63 local n
      int kc = id & 7;        // 8 k-chunks of 8
      f16x8 o;
#pragma unroll
      for (int j = 0; j < 8; ++j) o[j] = (f16)tile[kc * 8 + j][nl];
      int n = n0 + nl;
      int gk = (k0 >> 3) + kc;       // k0 is 64-aligned -> gk&3 == kc&3
      int p = (gk & ~3) | ((gk ^ ((n >> 1) & 3)) & 3);
      *(f16x8*)&Wt[(size_t)n * HID + p * 8] = o;
    }
  }
}

// ---------------- kernel 1: QKV GEMM (round-0 128x128, measured 117us) ----
__global__ __launch_bounds__(256, 3)
void qkv_gemm(const f16* __restrict__ xh, const f16* __restrict__ Wt,
              const float* __restrict__ bias, const int* __restrict__ lens,
              f16* __restrict__ Qh, f16* __restrict__ Kh, f16* __restrict__ Vt) {
  __shared__ f16 As[2 * 128 * 32];   // 16 KB  [half][row][32]
  __shared__ f16 Bs[2 * 128 * 32];   // 16 KB

  const int tid = threadIdx.x;
  const int wave = tid >> 6, lane = tid & 63;
  const int lr = lane & 15, quad = lane >> 4;
  const int nblk = blockIdx.x;   // 0..47  (t,h)
  const int mblk = blockIdx.y;   // 0..63
  const int m0 = mblk * 128;
  const int b = m0 >> 11;
  const int s0 = m0 & (SEQ - 1);
  const int len = get_len(lens, b);
  if (s0 >= len) return;         // fully-dead M-tile
  const int n0 = nblk * 128;
  const int wr = (wave >> 1) * 64;
  const int wc = (wave & 1) * 64;

  f32x4 acc[4][4] = {};
  const char* xbase = (const char*)xh + (size_t)m0 * (HID * 2);
  const char* wbase = (const char*)Wt + (size_t)n0 * (HID * 2);

  for (int k0 = 0; k0 < HID; k0 += 64) {
    __syncthreads();
#pragma unroll
    for (int i = 0; i < 4; ++i) {
      int slot = wave * 4 + i;          // 0..15
      int hh = slot >> 3;               // k-half
      int sub = slot & 7;
      int row = sub * 16 + (lane >> 2);
      size_t gcol = (size_t)k0 * 2 + hh * 64 + (lane & 3) * 16;
      async_copy16(&As[slot * 512], xbase + (size_t)row * (HID * 2) + gcol);
      async_copy16(&Bs[slot * 512], wbase + (size_t)row * (HID * 2) + gcol);
    }
    __syncthreads();

#pragma unroll
    for (int hh = 0; hh < 2; ++hh) {
      f16x8 a[4], bf[4];
#pragma unroll
      for (int mt = 0; mt < 4; ++mt) {
        int row = wr + mt * 16 + lr;
        int c = quad ^ ((row >> 1) & 3);
        a[mt] = *(const f16x8*)&As[hh * 4096 + row * 32 + c * 8];
      }
#pragma unroll
      for (int nt = 0; nt < 4; ++nt) {
        int row = wc + nt * 16 + lr;
        int c = quad ^ ((row >> 1) & 3);
        bf[nt] = *(const f16x8*)&Bs[hh * 4096 + row * 32 + c * 8];
      }
#pragma unroll
      for (int mt = 0; mt < 4; ++mt)
#pragma unroll
        for (int nt = 0; nt < 4; ++nt)
          acc[mt][nt] = __builtin_amdgcn_mfma_f32_16x16x32_f16(a[mt], bf[nt],
                                                               acc[mt][nt], 0, 0, 0);
    }
  }

  const int t = nblk >> 4;        // 0=q 1=k 2=v
  const int h = nblk & 15;
  const size_t bhoff = (size_t)(b * NH + h);

  if (t == 0) {
    f16* qp = Qh + bhoff * (SEQ * HD);
#pragma unroll
    for (int nt = 0; nt < 4; ++nt) {
      int d = wc + nt * 16 + lr;
      float bv = bias[n0 + d];
#pragma unroll
      for (int mt = 0; mt < 4; ++mt) {
        int sb = s0 + wr + mt * 16 + quad * 4;
#pragma unroll
        for (int r = 0; r < 4; ++r)
          qp[(size_t)(sb + r) * HD + d] = (f16)((acc[mt][nt][r] + bv) * QSCALE);
      }
    }
  } else if (t == 1) {
    f16* kp = Kh + bhoff * (SEQ * HD);
#pragma unroll
    for (int nt = 0; nt < 4; ++nt) {
      int d = wc + nt * 16 + lr;
      float bv = bias[n0 + d];
#pragma unroll
      for (int mt = 0; mt < 4; ++mt) {
        int sb = s0 + wr + mt * 16 + quad * 4;
#pragma unroll
        for (int r = 0; r < 4; ++r) {
          int s = sb + r;
          int c = (d >> 3) ^ (s & 15);            // chunk swizzle by s
          kp[(size_t)s * HD + c * 8 + (d & 7)] = (f16)(acc[mt][nt][r] + bv);
        }
      }
    }
  } else {
    f16* vp = Vt + bhoff * (HD * SEQ);            // transposed plane [d][s]
#pragma unroll
    for (int nt = 0; nt < 4; ++nt) {
      int d = wc + nt * 16 + lr;
      float bv = bias[n0 + d];
#pragma unroll
      for (int mt = 0; mt < 4; ++mt) {
        int sb = s0 + wr + mt * 16 + quad * 4;    // multiple of 4
        f16x4 pk;
#pragma unroll
        for (int r = 0; r < 4; ++r) pk[r] = (f16)(acc[mt][nt][r] + bv);
        int p = (sb >> 3) ^ (d & 7);              // s-chunk swizzle by d
        *(f16x4*)&vp[(size_t)d * SEQ + p * 8 + (sb & 7)] = pk;
      }
    }
  }
}

// ---------------- kernel 2: flash attention, in-register P v2 --------------
// 256 threads (4 waves x 32 q-rows), swapped QK^T (S^T in regs; P never
// touches LDS), PV via mfma_16x16x16 B-frag identity. v2 = v1 (fragment
// algebra proven by absmax pass) + DOUBLE-BUFFERED K/V staging with ONE
// barrier per tile:
//   { stage(buf^1, kt+1); QK(cur); mask; softmax; PV(cur); W0; bar }
// The vmcnt(0) is covered by the full tile's compute (~700-900 cyc/wave)
// instead of v1's two mid-tile drains with <500 cyc cover. WAR on buf^1 is
// safe: its last readers finished before the PREVIOUS end-of-tile barrier.
// LDS 64KB -> 2 blocks/CU (launch_bounds(256,2): VGPR cap 256, no spill).
__global__ __launch_bounds__(256, 2)
void attn(const f16* __restrict__ Qh, const f16* __restrict__ Kh,
          const f16* __restrict__ Vt, const int* __restrict__ lens,
          float* __restrict__ out) {
  __shared__ f16 Ks[2][64 * 128];   // [buf][key][d]  swizzled, 2x16KB
  __shared__ f16 Vs[2][128 * 64];   // [buf][d][key]  swizzled, 2x16KB

  const int tid = threadIdx.x, wave = tid >> 6, lane = tid & 63;
  const int lr = lane & 15, quad = lane >> 4;
  // decode XCD-swizzled id: id = (bh&7) + 8*(qt + 16*(bh>>3))
  const int id = blockIdx.x;
  const int bhlo = id & 7;
  const int r3 = id >> 3;
  const int qt = r3 & 15;
  const int bh = ((r3 >> 4) << 3) | bhlo;
  const int b = bh >> 4, h = bh & 15;
  const int len = get_len(lens, b);
  const int q0 = qt * 128;
  const size_t bho = (size_t)(b * NH + h);
  float* obase = out + bho * (size_t)(SEQ * HD);

  if (q0 >= len) {               // fully-invalid q-tile: write exact zeros
    f32x4 z = {0.f, 0.f, 0.f, 0.f};
#pragma unroll
    for (int i = 0; i < 16; ++i) {
      int idx = tid + i * 256;
      *(f32x4*)&obase[(size_t)q0 * HD + (size_t)idx * 4] = z;
    }
    return;
  }

  // Q fragments resident in registers: wave owns 32 q-rows (2 groups of 16)
  f16x8 qa[2][4];
  {
    const f16* qp = Qh + bho * (size_t)(SEQ * HD);
#pragma unroll
    for (int rg = 0; rg < 2; ++rg) {
      int row = q0 + wave * 32 + rg * 16 + lr;
#pragma unroll
      for (int ks = 0; ks < 4; ++ks)
        qa[rg][ks] = *(const f16x8*)&qp[(size_t)row * HD + ks * 32 + quad * 8];
    }
  }

  float lrow[2] = {0.f, 0.f};
  f32x4 oacc[2][8] = {};

  const char* kpl = (const char*)(Kh + bho * (size_t)(SEQ * HD));
  const char* vpl = (const char*)(Vt + bho * (size_t)(HD * SEQ));

  const int nkt = (len + 63) >> 6;

  // DMA staging: 16 slots of 1KB per buffer for K and V; wave stages 4 each.
  // LDS dest = slot base (wave-uniform); HW scatters lane i at base + i*16.
  // K slot: keys slot*4..+3, all 128 d (row-linear, already chunk-swizzled).
  // V slot: d-rows slot*8..+7, 64 keys (row-linear, already chunk-swizzled).
  auto stageK = [&](int bf, int kt) {
    size_t koff = (size_t)kt * 64;
#pragma unroll
    for (int j = 0; j < 4; ++j) {
      int slot = wave * 4 + j;
      const char* src = kpl +
          ((koff + slot * 4 + (lane >> 4)) * HD + (size_t)(lane & 15) * 8) * 2;
      async_copy16(&Ks[bf][slot * 512], src);
    }
  };
  auto stageV = [&](int bf, int kt) {
    size_t koff = (size_t)kt * 64;
#pragma unroll
    for (int j = 0; j < 4; ++j) {
      int slot = wave * 4 + j;
      const char* src = vpl +
          ((size_t)(slot * 8 + (lane >> 3)) * SEQ + koff + (size_t)(lane & 7) * 8) * 2;
      async_copy16(&Vs[bf][slot * 512], src);
    }
  };

  stageK(0, 0);
  stageV(0, 0);
  asm volatile("s_waitcnt vmcnt(0)" ::: "memory");
  __builtin_amdgcn_s_barrier();

  for (int kt = 0; kt < nkt; ++kt) {
    const int cur = kt & 1;
    if (kt + 1 < nkt) {            // prefetch next tile into the other buffer
      stageK(cur ^ 1, kt + 1);
      stageV(cur ^ 1, kt + 1);
    }

    // S^T = K @ Q^T  (exp2 domain; scale pre-folded into Q)
    f32x4 sacc[2][4] = {};
#pragma unroll
    for (int ks = 0; ks < 4; ++ks) {
      f16x8 kb[4];
#pragma unroll
      for (int nt = 0; nt < 4; ++nt) {
        int key = nt * 16 + lr;
        int c = (ks * 4 + quad) ^ (key & 15);
        kb[nt] = *(const f16x8*)&Ks[cur][key * 128 + c * 8];
      }
#pragma unroll
      for (int nt = 0; nt < 4; ++nt) {
        sacc[0][nt] = __builtin_amdgcn_mfma_f32_16x16x32_f16(kb[nt], qa[0][ks],
                                                             sacc[0][nt], 0, 0, 0);
        sacc[1][nt] = __builtin_amdgcn_mfma_f32_16x16x32_f16(kb[nt], qa[1][ks],
                                                             sacc[1][nt], 0, 0, 0);
      }
    }

    // jagged mask (last tile only): key = kbase + nt*16 + quad*4 + r
    const int kbase = kt * 64;
    if (kbase + 64 > len) {
#pragma unroll
      for (int nt = 0; nt < 4; ++nt)
#pragma unroll
        for (int r = 0; r < 4; ++r)
          if (kbase + nt * 16 + quad * 4 + r >= len) {
            sacc[0][nt][r] = -3.0e38f;
            sacc[1][nt][r] = -3.0e38f;
          }
    }

    // fixed-shift softmax in-register: p = exp2(s); pack to f16 B-frags
    f16x4 pb[2][4];
#pragma unroll
    for (int rg = 0; rg < 2; ++rg)
#pragma unroll
      for (int nt = 0; nt < 4; ++nt) {
        float e0 = __builtin_amdgcn_exp2f(sacc[rg][nt][0]);
        float e1 = __builtin_amdgcn_exp2f(sacc[rg][nt][1]);
        float e2 = __builtin_amdgcn_exp2f(sacc[rg][nt][2]);
        float e3 = __builtin_amdgcn_exp2f(sacc[rg][nt][3]);
        lrow[rg] += (e0 + e1) + (e2 + e3);
        f16x4 pk = {(f16)e0, (f16)e1, (f16)e2, (f16)e3};
        pb[rg][nt] = pk;
      }

    // O^T += V^T @ P^T  (A = V-frag k=quad*4..+3, B = pb)
#pragma unroll
    for (int dt = 0; dt < 8; ++dt) {
      int d = dt * 16 + lr;
      f16x4 va[4];
#pragma unroll
      for (int nt = 0; nt < 4; ++nt) {
        int cc = (nt * 2 + (quad >> 1)) ^ (d & 7);
        va[nt] = *(const f16x4*)&Vs[cur][d * 64 + cc * 8 + (quad & 1) * 4];
      }
#pragma unroll
      for (int nt = 0; nt < 4; ++nt) {
        oacc[0][dt] = __builtin_amdgcn_mfma_f32_16x16x16f16(va[nt], pb[0][nt],
                                                            oacc[0][dt], 0, 0, 0);
        oacc[1][dt] = __builtin_amdgcn_mfma_f32_16x16x16f16(va[nt], pb[1][nt],
                                                            oacc[1][dt], 0, 0, 0);
      }
    }

    // next tile's DMAs (issued at top) drain under this tile's compute
    asm volatile("s_waitcnt vmcnt(0)" ::: "memory");
    __builtin_amdgcn_s_barrier();
  }

  // finalize: lanes lr, lr+16, lr+32, lr+48 share q-row -> xor 16/32
  float linv[2];
#pragma unroll
  for (int rg = 0; rg < 2; ++rg) {
    float l = lrow[rg];
    l += __shfl_xor(l, 16);
    l += __shfl_xor(l, 32);
    linv[rg] = 1.0f / l;
  }
#pragma unroll
  for (int rg = 0; rg < 2; ++rg) {
    int s = q0 + wave * 32 + rg * 16 + lr;
    bool valid = s < len;
#pragma unroll
    for (int dt = 0; dt < 8; ++dt) {
      f32x4 o;
#pragma unroll
      for (int r = 0; r < 4; ++r)
        o[r] = valid ? oacc[rg][dt][r] * linv[rg] : 0.0f;
      *(f32x4*)&obase[(size_t)s * HD + dt * 16 + quad * 4] = o;
    }
  }
}

extern "C" void kernel_launch(void* const* d_in, const int* in_sizes, int n_in,
                              void* d_out, int out_size, void* d_ws, size_t ws_size,
                              hipStream_t stream) {
  const float* x = (const float*)d_in[0];
  const float* W = (const float*)d_in[1];
  const float* bias = (const float*)d_in[2];
  const int* lens = (const int*)d_in[3];
  float* out = (float*)d_out;

  char* ws = (char*)d_ws;
  size_t off = 0;
  f16* xh = (f16*)(ws + off); off += (size_t)BATCH * SEQ * HID * 2;   // 32MB
  f16* Wt = (f16*)(ws + off); off += (size_t)N3 * HID * 2;            // 24MB
  f16* Qh = (f16*)(ws + off); off += (size_t)BATCH * NH * SEQ * HD * 2;
  f16* Kh = (f16*)(ws + off); off += (size_t)BATCH * NH * SEQ * HD * 2;
  f16* Vt = (f16*)(ws + off); off += (size_t)BATCH * NH * SEQ * HD * 2;
  // total ws use: ~152 MB

  cvt_fused<<<8192 + 3072, 256, 0, stream>>>(x, xh, W, Wt);
  qkv_gemm<<<dim3(48, 64), 256, 0, stream>>>(xh, Wt, bias, lens, Qh, Kh, Vt);
  attn<<<1024, 256, 0, stream>>>(Qh, Kh, Vt, lens, out);
}

// Round 9
// 328.202 us; speedup vs baseline: 1.1357x; 1.0169x over previous
//
#include <hip/hip_runtime.h>
#include <stdint.h>

#define BATCH 4
#define SEQ   2048
#define NH    16
#define HD    128
#define HID   2048
#define N3    6144

typedef _Float16 f16;
typedef _Float16 f16x8 __attribute__((ext_vector_type(8)));
typedef _Float16 f16x4 __attribute__((ext_vector_type(4)));
typedef float    f32x4 __attribute__((ext_vector_type(4)));

// log2(e)/sqrt(HD): softmax computed in exp2 domain, scale folded into Q
#define QSCALE 0.1275313895f

// lengths may arrive as int32 or int64. int64 storage of lengths[0]=2048 puts
// 0 at word index 1; int32 puts 1024.
__device__ __forceinline__ int get_len(const int* L, int b) {
  return (L[1] == 0) ? L[2 * b] : L[b];
}

// NOTE: lds_uniform MUST be wave-uniform; HW writes lane i at base + i*16.
__device__ __forceinline__ void async_copy16(void* lds_uniform, const void* gptr) {
  __builtin_amdgcn_global_load_lds(
      (const __attribute__((address_space(1))) void*)(uintptr_t)gptr,
      (__attribute__((address_space(3))) void*)(uint32_t)(uintptr_t)lds_uniform,
      16, 0, 0);
}

// ---------------- kernel 0: fused x->fp16 and W->Wt fp16 ------------------
// R2's 64B-window chunk swizzle (measured 0 LDS conflicts):
//   p = (g & ~3) | ((g ^ ((row>>1)&3)) & 3)   [g = 8-f16 chunk index]
// R8 changes: (a) skip x rows in fully-dead 128-tiles (qkv never reads them;
// partially-dead tiles still converted so V-garbage stays finite), (b) x
// loads vectorized as 2x f32x4 (was 8 scalar dwords).
__global__ __launch_bounds__(256) void cvt_fused(const float* __restrict__ x,
                                                 f16* __restrict__ xh,
                                                 const float* __restrict__ W,
                                                 f16* __restrict__ Wt,
                                                 const int* __restrict__ lens) {
  __shared__ float tile[64][65];
  if (blockIdx.x < 8192) {
    // ---- x [8192][2048] fp32 -> xh fp16, swizzled ----
    int m = blockIdx.x;                        // one row per block
    int s = m & (SEQ - 1);
    if ((s & ~127) >= get_len(lens, m >> 11)) return;  // fully-dead tile
    int g = threadIdx.x;                       // 8-elem chunk within row
    int p = (g & ~3) | ((g ^ ((m >> 1) & 3)) & 3);
    const float* src = x + (size_t)m * HID + g * 8;
    f32x4 v0 = *(const f32x4*)&src[0];
    f32x4 v1 = *(const f32x4*)&src[4];
    f16x8 o;
#pragma unroll
    for (int j = 0; j < 4; ++j) { o[j] = (f16)v0[j]; o[j + 4] = (f16)v1[j]; }
    *(f16x8*)&xh[(size_t)m * HID + p * 8] = o;
  } else {
    // ---- W [K=2048][N=6144] fp32 -> Wt [N][K] fp16, swizzled ----
    int bid = blockIdx.x - 8192;               // 0..3071
    const int n0 = (bid % 96) * 64;
    const int k0 = (bid / 96) * 64;
    const int tid = threadIdx.x;
#pragma unroll
    for (int i = 0; i < 4; ++i) {
      int id = tid + i * 256;
      int kr = id >> 4, nc = id & 15;
      f32x4 v = *(const f32x4*)&W[(size_t)(k0 + kr) * N3 + n0 + nc * 4];
#pragma unroll
      for (int j = 0; j < 4; ++j) tile[kr][nc * 4 + j] = v[j];
    }
    __syncthreads();
#pragma unroll
    for (int i = 0; i < 2; ++i) {
      int id = tid + i * 256;
      int nl = id >> 3;       // 0..63 local n
      int kc = id & 7;        // 8 k-chunks of 8
      f16x8 o;
#pragma unroll
      for (int j = 0; j < 8; ++j) o[j] = (f16)tile[kc * 8 + j][nl];
      int n = n0 + nl;
      int gk = (k0 >> 3) + kc;       // k0 is 64-aligned -> gk&3 == kc&3
      int p = (gk & ~3) | ((gk ^ ((n >> 1) & 3)) & 3);
      *(f16x8*)&Wt[(size_t)n * HID + p * 8] = o;
    }
  }
}

// ---------------- kernel 1: QKV GEMM (round-0 128x128, measured 117us) ----
__global__ __launch_bounds__(256, 3)
void qkv_gemm(const f16* __restrict__ xh, const f16* __restrict__ Wt,
              const float* __restrict__ bias, const int* __restrict__ lens,
              f16* __restrict__ Qh, f16* __restrict__ Kh, f16* __restrict__ Vt) {
  __shared__ f16 As[2 * 128 * 32];   // 16 KB  [half][row][32]
  __shared__ f16 Bs[2 * 128 * 32];   // 16 KB

  const int tid = threadIdx.x;
  const int wave = tid >> 6, lane = tid & 63;
  const int lr = lane & 15, quad = lane >> 4;
  const int nblk = blockIdx.x;   // 0..47  (t,h)
  const int mblk = blockIdx.y;   // 0..63
  const int m0 = mblk * 128;
  const int b = m0 >> 11;
  const int s0 = m0 & (SEQ - 1);
  const int len = get_len(lens, b);
  if (s0 >= len) return;         // fully-dead M-tile
  const int n0 = nblk * 128;
  const int wr = (wave >> 1) * 64;
  const int wc = (wave & 1) * 64;

  f32x4 acc[4][4] = {};
  const char* xbase = (const char*)xh + (size_t)m0 * (HID * 2);
  const char* wbase = (const char*)Wt + (size_t)n0 * (HID * 2);

  for (int k0 = 0; k0 < HID; k0 += 64) {
    __syncthreads();
#pragma unroll
    for (int i = 0; i < 4; ++i) {
      int slot = wave * 4 + i;          // 0..15
      int hh = slot >> 3;               // k-half
      int sub = slot & 7;
      int row = sub * 16 + (lane >> 2);
      size_t gcol = (size_t)k0 * 2 + hh * 64 + (lane & 3) * 16;
      async_copy16(&As[slot * 512], xbase + (size_t)row * (HID * 2) + gcol);
      async_copy16(&Bs[slot * 512], wbase + (size_t)row * (HID * 2) + gcol);
    }
    __syncthreads();

#pragma unroll
    for (int hh = 0; hh < 2; ++hh) {
      f16x8 a[4], bf[4];
#pragma unroll
      for (int mt = 0; mt < 4; ++mt) {
        int row = wr + mt * 16 + lr;
        int c = quad ^ ((row >> 1) & 3);
        a[mt] = *(const f16x8*)&As[hh * 4096 + row * 32 + c * 8];
      }
#pragma unroll
      for (int nt = 0; nt < 4; ++nt) {
        int row = wc + nt * 16 + lr;
        int c = quad ^ ((row >> 1) & 3);
        bf[nt] = *(const f16x8*)&Bs[hh * 4096 + row * 32 + c * 8];
      }
#pragma unroll
      for (int mt = 0; mt < 4; ++mt)
#pragma unroll
        for (int nt = 0; nt < 4; ++nt)
          acc[mt][nt] = __builtin_amdgcn_mfma_f32_16x16x32_f16(a[mt], bf[nt],
                                                               acc[mt][nt], 0, 0, 0);
    }
  }

  const int t = nblk >> 4;        // 0=q 1=k 2=v
  const int h = nblk & 15;
  const size_t bhoff = (size_t)(b * NH + h);

  if (t == 0) {
    f16* qp = Qh + bhoff * (SEQ * HD);
#pragma unroll
    for (int nt = 0; nt < 4; ++nt) {
      int d = wc + nt * 16 + lr;
      float bv = bias[n0 + d];
#pragma unroll
      for (int mt = 0; mt < 4; ++mt) {
        int sb = s0 + wr + mt * 16 + quad * 4;
#pragma unroll
        for (int r = 0; r < 4; ++r)
          qp[(size_t)(sb + r) * HD + d] = (f16)((acc[mt][nt][r] + bv) * QSCALE);
      }
    }
  } else if (t == 1) {
    f16* kp = Kh + bhoff * (SEQ * HD);
#pragma unroll
    for (int nt = 0; nt < 4; ++nt) {
      int d = wc + nt * 16 + lr;
      float bv = bias[n0 + d];
#pragma unroll
      for (int mt = 0; mt < 4; ++mt) {
        int sb = s0 + wr + mt * 16 + quad * 4;
#pragma unroll
        for (int r = 0; r < 4; ++r) {
          int s = sb + r;
          int c = (d >> 3) ^ (s & 15);            // chunk swizzle by s
          kp[(size_t)s * HD + c * 8 + (d & 7)] = (f16)(acc[mt][nt][r] + bv);
        }
      }
    }
  } else {
    f16* vp = Vt + bhoff * (HD * SEQ);            // transposed plane [d][s]
#pragma unroll
    for (int nt = 0; nt < 4; ++nt) {
      int d = wc + nt * 16 + lr;
      float bv = bias[n0 + d];
#pragma unroll
      for (int mt = 0; mt < 4; ++mt) {
        int sb = s0 + wr + mt * 16 + quad * 4;    // multiple of 4
        f16x4 pk;
#pragma unroll
        for (int r = 0; r < 4; ++r) pk[r] = (f16)(acc[mt][nt][r] + bv);
        int p = (sb >> 3) ^ (d & 7);              // s-chunk swizzle by d
        *(f16x4*)&vp[(size_t)d * SEQ + p * 8 + (sb & 7)] = pk;
      }
    }
  }
}

// ---------------- kernel 2: flash attention, in-register P v2 --------------
// 256 threads (4 waves x 32 q-rows), swapped QK^T (S^T in regs; P never
// touches LDS), PV via mfma_16x16x16 B-frag identity. Double-buffered K/V
// staging with one barrier per tile (proven passing, round 8):
//   { stage(buf^1, kt+1); QK(cur); mask; softmax; PV(cur); W0; bar }
__global__ __launch_bounds__(256, 2)
void attn(const f16* __restrict__ Qh, const f16* __restrict__ Kh,
          const f16* __restrict__ Vt, const int* __restrict__ lens,
          float* __restrict__ out) {
  __shared__ f16 Ks[2][64 * 128];   // [buf][key][d]  swizzled, 2x16KB
  __shared__ f16 Vs[2][128 * 64];   // [buf][d][key]  swizzled, 2x16KB

  const int tid = threadIdx.x, wave = tid >> 6, lane = tid & 63;
  const int lr = lane & 15, quad = lane >> 4;
  // decode XCD-swizzled id: id = (bh&7) + 8*(qt + 16*(bh>>3))
  const int id = blockIdx.x;
  const int bhlo = id & 7;
  const int r3 = id >> 3;
  const int qt = r3 & 15;
  const int bh = ((r3 >> 4) << 3) | bhlo;
  const int b = bh >> 4, h = bh & 15;
  const int len = get_len(lens, b);
  const int q0 = qt * 128;
  const size_t bho = (size_t)(b * NH + h);
  float* obase = out + bho * (size_t)(SEQ * HD);

  if (q0 >= len) {               // fully-invalid q-tile: write exact zeros
    f32x4 z = {0.f, 0.f, 0.f, 0.f};
#pragma unroll
    for (int i = 0; i < 16; ++i) {
      int idx = tid + i * 256;
      *(f32x4*)&obase[(size_t)q0 * HD + (size_t)idx * 4] = z;
    }
    return;
  }

  // Q fragments resident in registers: wave owns 32 q-rows (2 groups of 16)
  f16x8 qa[2][4];
  {
    const f16* qp = Qh + bho * (size_t)(SEQ * HD);
#pragma unroll
    for (int rg = 0; rg < 2; ++rg) {
      int row = q0 + wave * 32 + rg * 16 + lr;
#pragma unroll
      for (int ks = 0; ks < 4; ++ks)
        qa[rg][ks] = *(const f16x8*)&qp[(size_t)row * HD + ks * 32 + quad * 8];
    }
  }

  float lrow[2] = {0.f, 0.f};
  f32x4 oacc[2][8] = {};

  const char* kpl = (const char*)(Kh + bho * (size_t)(SEQ * HD));
  const char* vpl = (const char*)(Vt + bho * (size_t)(HD * SEQ));

  const int nkt = (len + 63) >> 6;

  // DMA staging: 16 slots of 1KB per buffer for K and V; wave stages 4 each.
  // LDS dest = slot base (wave-uniform); HW scatters lane i at base + i*16.
  auto stageK = [&](int bf, int kt) {
    size_t koff = (size_t)kt * 64;
#pragma unroll
    for (int j = 0; j < 4; ++j) {
      int slot = wave * 4 + j;
      const char* src = kpl +
          ((koff + slot * 4 + (lane >> 4)) * HD + (size_t)(lane & 15) * 8) * 2;
      async_copy16(&Ks[bf][slot * 512], src);
    }
  };
  auto stageV = [&](int bf, int kt) {
    size_t koff = (size_t)kt * 64;
#pragma unroll
    for (int j = 0; j < 4; ++j) {
      int slot = wave * 4 + j;
      const char* src = vpl +
          ((size_t)(slot * 8 + (lane >> 3)) * SEQ + koff + (size_t)(lane & 7) * 8) * 2;
      async_copy16(&Vs[bf][slot * 512], src);
    }
  };

  stageK(0, 0);
  stageV(0, 0);
  asm volatile("s_waitcnt vmcnt(0)" ::: "memory");
  __builtin_amdgcn_s_barrier();

  for (int kt = 0; kt < nkt; ++kt) {
    const int cur = kt & 1;
    if (kt + 1 < nkt) {            // prefetch next tile into the other buffer
      stageK(cur ^ 1, kt + 1);
      stageV(cur ^ 1, kt + 1);
    }

    // S^T = K @ Q^T  (exp2 domain; scale pre-folded into Q)
    f32x4 sacc[2][4] = {};
#pragma unroll
    for (int ks = 0; ks < 4; ++ks) {
      f16x8 kb[4];
#pragma unroll
      for (int nt = 0; nt < 4; ++nt) {
        int key = nt * 16 + lr;
        int c = (ks * 4 + quad) ^ (key & 15);
        kb[nt] = *(const f16x8*)&Ks[cur][key * 128 + c * 8];
      }
#pragma unroll
      for (int nt = 0; nt < 4; ++nt) {
        sacc[0][nt] = __builtin_amdgcn_mfma_f32_16x16x32_f16(kb[nt], qa[0][ks],
                                                             sacc[0][nt], 0, 0, 0);
        sacc[1][nt] = __builtin_amdgcn_mfma_f32_16x16x32_f16(kb[nt], qa[1][ks],
                                                             sacc[1][nt], 0, 0, 0);
      }
    }

    // jagged mask (last tile only): key = kbase + nt*16 + quad*4 + r
    const int kbase = kt * 64;
    if (kbase + 64 > len) {
#pragma unroll
      for (int nt = 0; nt < 4; ++nt)
#pragma unroll
        for (int r = 0; r < 4; ++r)
          if (kbase + nt * 16 + quad * 4 + r >= len) {
            sacc[0][nt][r] = -3.0e38f;
            sacc[1][nt][r] = -3.0e38f;
          }
    }

    // fixed-shift softmax in-register: p = exp2(s); pack to f16 B-frags
    f16x4 pb[2][4];
#pragma unroll
    for (int rg = 0; rg < 2; ++rg)
#pragma unroll
      for (int nt = 0; nt < 4; ++nt) {
        float e0 = __builtin_amdgcn_exp2f(sacc[rg][nt][0]);
        float e1 = __builtin_amdgcn_exp2f(sacc[rg][nt][1]);
        float e2 = __builtin_amdgcn_exp2f(sacc[rg][nt][2]);
        float e3 = __builtin_amdgcn_exp2f(sacc[rg][nt][3]);
        lrow[rg] += (e0 + e1) + (e2 + e3);
        f16x4 pk = {(f16)e0, (f16)e1, (f16)e2, (f16)e3};
        pb[rg][nt] = pk;
      }

    // O^T += V^T @ P^T  (A = V-frag k=quad*4..+3, B = pb)
#pragma unroll
    for (int dt = 0; dt < 8; ++dt) {
      int d = dt * 16 + lr;
      f16x4 va[4];
#pragma unroll
      for (int nt = 0; nt < 4; ++nt) {
        int cc = (nt * 2 + (quad >> 1)) ^ (d & 7);
        va[nt] = *(const f16x4*)&Vs[cur][d * 64 + cc * 8 + (quad & 1) * 4];
      }
#pragma unroll
      for (int nt = 0; nt < 4; ++nt) {
        oacc[0][dt] = __builtin_amdgcn_mfma_f32_16x16x16f16(va[nt], pb[0][nt],
                                                            oacc[0][dt], 0, 0, 0);
        oacc[1][dt] = __builtin_amdgcn_mfma_f32_16x16x16f16(va[nt], pb[1][nt],
                                                            oacc[1][dt], 0, 0, 0);
      }
    }

    // next tile's DMAs (issued at top) drain under this tile's compute
    asm volatile("s_waitcnt vmcnt(0)" ::: "memory");
    __builtin_amdgcn_s_barrier();
  }

  // finalize: lanes lr, lr+16, lr+32, lr+48 share q-row -> xor 16/32
  float linv[2];
#pragma unroll
  for (int rg = 0; rg < 2; ++rg) {
    float l = lrow[rg];
    l += __shfl_xor(l, 16);
    l += __shfl_xor(l, 32);
    linv[rg] = 1.0f / l;
  }
#pragma unroll
  for (int rg = 0; rg < 2; ++rg) {
    int s = q0 + wave * 32 + rg * 16 + lr;
    bool valid = s < len;
#pragma unroll
    for (int dt = 0; dt < 8; ++dt) {
      f32x4 o;
#pragma unroll
      for (int r = 0; r < 4; ++r)
        o[r] = valid ? oacc[rg][dt][r] * linv[rg] : 0.0f;
      *(f32x4*)&obase[(size_t)s * HD + dt * 16 + quad * 4] = o;
    }
  }
}

extern "C" void kernel_launch(void* const* d_in, const int* in_sizes, int n_in,
                              void* d_out, int out_size, void* d_ws, size_t ws_size,
                              hipStream_t stream) {
  const float* x = (const float*)d_in[0];
  const float* W = (const float*)d_in[1];
  const float* bias = (const float*)d_in[2];
  const int* lens = (const int*)d_in[3];
  float* out = (float*)d_out;

  char* ws = (char*)d_ws;
  size_t off = 0;
  f16* xh = (f16*)(ws + off); off += (size_t)BATCH * SEQ * HID * 2;   // 32MB
  f16* Wt = (f16*)(ws + off); off += (size_t)N3 * HID * 2;            // 24MB
  f16* Qh = (f16*)(ws + off); off += (size_t)BATCH * NH * SEQ * HD * 2;
  f16* Kh = (f16*)(ws + off); off += (size_t)BATCH * NH * SEQ * HD * 2;
  f16* Vt = (f16*)(ws + off); off += (size_t)BATCH * NH * SEQ * HD * 2;
  // total ws use: ~152 MB

  cvt_fused<<<8192 + 3072, 256, 0, stream>>>(x, xh, W, Wt, lens);
  qkv_gemm<<<dim3(48, 64), 256, 0, stream>>>(xh, Wt, bias, lens, Qh, Kh, Vt);
  attn<<<1024, 256, 0, stream>>>(Qh, Kh, Vt, lens, out);
}